// Round 9
// baseline (119.441 us; speedup 1.0000x reference)
//
#include <hip/hip_runtime.h>
#include <hip/hip_bf16.h>
#include <math.h>
#include <stdint.h>

#define BB 4
#define SS 2048
#define DD 768
#define MM (BB*SS)       // 8192
#define NBLK 768         // rgemm grid

typedef __attribute__((ext_vector_type(4))) float  f32x4;
typedef __attribute__((ext_vector_type(8))) __bf16 bf16x8;
typedef __attribute__((ext_vector_type(4))) __bf16 bf16x4;

#define AS1 __attribute__((address_space(1)))
#define AS3 __attribute__((address_space(3)))

// ============ K0: combined front kernel ============
// blocks [0,144):     G = Wq @ Wk^T, 64x64 tiles (12x12), fp32 reg-staged
// blocks [144,529):   u = Wq@bk (192), v = Wk@bq (192), cb = bq.bk (1)
// blocks [529,2577):  LayerNorm, 4 rows/block (wave per row)
// blocks [2577,2609): att-flag + prior-superdiag gather + cnt zero
__global__ __launch_bounds__(256) void combined_kernel(
        const float* __restrict__ x, const float* __restrict__ lw,
        const float* __restrict__ lb, const float* __restrict__ wq,
        const float* __restrict__ wk, const float* __restrict__ bq,
        const float* __restrict__ bk, const int* __restrict__ att,
        const float* __restrict__ prior, __bf16* __restrict__ G,
        float* __restrict__ u, float* __restrict__ v, float* __restrict__ cb,
        __bf16* __restrict__ h, int* __restrict__ fl, float* __restrict__ prsup,
        int* __restrict__ cnt) {
    __shared__ __attribute__((aligned(16))) __bf16 As[64][32];
    __shared__ __attribute__((aligned(16))) __bf16 Bs[64][32];
    const int bid = blockIdx.x;
    if (bid >= 2577) {
        // ---- gather ----
        const int idx = (bid - 2577) * 256 + threadIdx.x;   // 0..8191
        if (idx == 0) cnt[0] = 0;
        const int b = idx >> 11, s = idx & 2047;
        const bool au = (s < SS - 1) && ((att[((size_t)b * SS + s) * SS + (s + 1)] & 1) != 0);
        const bool ad = (s > 0)      && ((att[((size_t)b * SS + s) * SS + (s - 1)] & 1) != 0);
        fl[idx] = (au ? 1 : 0) | (ad ? 2 : 0);
        if (s < SS - 1)
            prsup[idx] = prior[((size_t)b * SS + s) * SS + s + 1];
        return;
    }
    if (bid >= 529) {
        // ---- LayerNorm ----
        const int row = (bid - 529) * 4 + (threadIdx.x >> 6);
        const int lane = threadIdx.x & 63;
        const float* xr = x + (size_t)row * DD + lane * 12;
        f32x4 a0 = *(const f32x4*)(xr), a1 = *(const f32x4*)(xr + 4), a2 = *(const f32x4*)(xr + 8);
        float xs[12];
#pragma unroll
        for (int c = 0; c < 4; c++) { xs[c] = a0[c]; xs[4 + c] = a1[c]; xs[8 + c] = a2[c]; }
        float s = 0.f, ss = 0.f;
#pragma unroll
        for (int c = 0; c < 12; c++) { s += xs[c]; ss += xs[c] * xs[c]; }
#pragma unroll
        for (int o = 1; o < 64; o <<= 1) { s += __shfl_xor(s, o); ss += __shfl_xor(ss, o); }
        const float mu = s * (1.0f / DD);
        const float var = ss * (1.0f / DD) - mu * mu;
        const float rstd = 1.0f / sqrtf(var + 1e-12f);
        const float* wp = lw + lane * 12; const float* bp = lb + lane * 12;
        f32x4 w0 = *(const f32x4*)(wp), w1 = *(const f32x4*)(wp + 4), w2 = *(const f32x4*)(wp + 8);
        f32x4 b0 = *(const f32x4*)(bp), b1 = *(const f32x4*)(bp + 4), b2 = *(const f32x4*)(bp + 8);
        bf16x4 o0, o1, o2;
#pragma unroll
        for (int c = 0; c < 4; c++) {
            o0[c] = (__bf16)((xs[c]     - mu) * rstd * w0[c] + b0[c]);
            o1[c] = (__bf16)((xs[4 + c] - mu) * rstd * w1[c] + b1[c]);
            o2[c] = (__bf16)((xs[8 + c] - mu) * rstd * w2[c] + b2[c]);
        }
        __bf16* hr = h + (size_t)row * DD + lane * 12;
        *(bf16x4*)(hr) = o0; *(bf16x4*)(hr + 4) = o1; *(bf16x4*)(hr + 8) = o2;
        return;
    }
    if (bid >= 144) {
        // ---- uvcb ----
        const int id = bid - 144;
        const int lane = threadIdx.x & 63, wv_ = threadIdx.x >> 6;
        if (id == 384) {
            if (wv_ != 0) return;
            float s = 0.f;
#pragma unroll
            for (int m = 0; m < 12; m++) s += bq[lane + 64 * m] * bk[lane + 64 * m];
#pragma unroll
            for (int o = 1; o < 64; o <<= 1) s += __shfl_xor(s, o);
            if (lane == 0) cb[0] = s;
            return;
        }
        const bool isU = id < 192;
        const int row = (isU ? id : id - 192) * 4 + wv_;
        const float* W = isU ? wq : wk;
        const float* bvec = isU ? bk : bq;
        const float* wr_ = W + (size_t)row * DD;
        float s = 0.f;
#pragma unroll
        for (int m = 0; m < 12; m++) s += wr_[lane + 64 * m] * bvec[lane + 64 * m];
#pragma unroll
        for (int o = 1; o < 64; o <<= 1) s += __shfl_xor(s, o);
        if (lane == 0) (isU ? u : v)[row] = s;
        return;
    }
    // ---- G-gemm: G[d,e] = sum_j wq[d,j] * wk[e,j], 64x64 tile ----
    const int m0 = (bid % 12) * 64;
    const int n0 = (bid / 12) * 64;
    const int t = threadIdx.x;
    const int wave = t >> 6, lane = t & 63;
    const int wr = wave >> 1, wc = wave & 1;
    const int srow = t >> 2, scol = (t & 3) * 8;    // 4 threads/row, 8 fp32 each
    f32x4 acc[2][2] = {};

    for (int k0 = 0; k0 < DD; k0 += 32) {
        const float* ga = wq + (size_t)(m0 + srow) * DD + k0 + scol;
        const float* gb = wk + (size_t)(n0 + srow) * DD + k0 + scol;
        f32x4 a0 = *(const f32x4*)(ga), a1 = *(const f32x4*)(ga + 4);
        f32x4 b0 = *(const f32x4*)(gb), b1 = *(const f32x4*)(gb + 4);
        bf16x8 av, bv;
#pragma unroll
        for (int c = 0; c < 4; c++) {
            av[c] = (__bf16)a0[c]; av[4 + c] = (__bf16)a1[c];
            bv[c] = (__bf16)b0[c]; bv[4 + c] = (__bf16)b1[c];
        }
        __syncthreads();
        *(bf16x8*)&As[srow][scol] = av;
        *(bf16x8*)&Bs[srow][scol] = bv;
        __syncthreads();
        const int r = lane & 15, ko = (lane >> 4) << 3;
        bf16x8 af[2], bvf[2];
#pragma unroll
        for (int i = 0; i < 2; i++) af[i]  = *(const bf16x8*)&As[wr * 32 + i * 16 + r][ko];
#pragma unroll
        for (int j = 0; j < 2; j++) bvf[j] = *(const bf16x8*)&Bs[wc * 32 + j * 16 + r][ko];
#pragma unroll
        for (int i = 0; i < 2; i++)
#pragma unroll
            for (int j = 0; j < 2; j++)
                acc[i][j] = __builtin_amdgcn_mfma_f32_16x16x32_bf16(af[i], bvf[j], acc[i][j], 0, 0, 0);
    }
#pragma unroll
    for (int i = 0; i < 2; i++) {
        const int mm = m0 + wr * 32 + i * 16 + (lane >> 4) * 4;
#pragma unroll
        for (int j = 0; j < 2; j++) {
            const int nn = n0 + wc * 32 + j * 16 + (lane & 15);
#pragma unroll
            for (int rr = 0; rr < 4; rr++)
                G[(size_t)(mm + rr) * DD + nn] = (__bf16)acc[i][j][rr];
        }
    }
}

// ============ K1: fused R-gemm + band dots + last-4-blocks scan ============
// GEMM/epilogue identical to R8. After partials are written, each block does
// __threadfence + atomicAdd(cnt); the 4 blocks seeing old>=764 acquire-fence
// and run the per-batch softmax/log2/prefix-scan (batch = old-764).
__global__ __launch_bounds__(256) void rgemm_kernel(const __bf16* __restrict__ A,
        const __bf16* __restrict__ Bt, const float* __restrict__ u,
        const float* __restrict__ v, float* __restrict__ du_part,
        float* __restrict__ dn_part, float* __restrict__ w_part,
        const float* __restrict__ cbp, const int* __restrict__ fl_i,
        const float* __restrict__ prsup, float* __restrict__ nb,
        double* __restrict__ P2, int* __restrict__ cnt) {
    __shared__ __attribute__((aligned(16))) union {
        struct { __bf16 As[2][64 * 32]; __bf16 Bs[2][128 * 32]; } g;   // 24 KB
        struct { float du[SS]; float dn[SS]; float w[SS]; float pd[SS]; double warr[256]; } s; // 34 KB
    } sm;
    __shared__ int sh_old;
    const int bid = blockIdx.x;
    const int mt = bid & 127, nt = bid >> 7;
    const int m0 = mt * 64, n0 = nt * 128;
    const int t = threadIdx.x;
    const int wave = t >> 6, lane = t & 63;
    const int wr = wave >> 1, wc = wave & 1;
    f32x4 acc[2][4] = {};

    const int rloc = lane >> 2;               // 0..15 row within wave-issue
    const int slot = lane & 3;                // 16B slot within 64B row
    const int rA = wave * 16 + rloc;          // tile-local row 0..63
    const int csw = (slot ^ ((rA >> 1) & 3)) << 3;   // swizzled element col

    const __bf16* gA  = A  + (size_t)(m0 + rA) * DD + csw;
    const __bf16* gB0 = Bt + (size_t)(n0 + rA) * DD + csw;
    const __bf16* gB1 = gB0 + (size_t)64 * DD;

#define STAGE(buf, koff)                                                                          \
    do {                                                                                          \
        char* asb_ = (char*)sm.g.As[buf];                                                         \
        char* bsb_ = (char*)sm.g.Bs[buf];                                                         \
        __builtin_amdgcn_global_load_lds((const AS1 void*)(gA  + (koff)), (AS3 void*)(asb_ + wave * 1024),        16, 0, 0); \
        __builtin_amdgcn_global_load_lds((const AS1 void*)(gB0 + (koff)), (AS3 void*)(bsb_ + wave * 1024),        16, 0, 0); \
        __builtin_amdgcn_global_load_lds((const AS1 void*)(gB1 + (koff)), (AS3 void*)(bsb_ + 4096 + wave * 1024), 16, 0, 0); \
    } while (0)

    STAGE(0, 0);
    __syncthreads();
    int cur = 0;
    const int r = lane & 15, ks = lane >> 4;   // logical 16B slot 0..3
#pragma unroll 1
    for (int kt = 0; kt < 24; kt++) {
        if (kt < 23) STAGE(cur ^ 1, (kt + 1) * 32);
        bf16x8 af[2], bvf[4];
#pragma unroll
        for (int i = 0; i < 2; i++) {
            const int R = wr * 32 + i * 16 + r;
            af[i] = *(const bf16x8*)&sm.g.As[cur][R * 32 + ((ks ^ ((R >> 1) & 3)) << 3)];
        }
#pragma unroll
        for (int j = 0; j < 4; j++) {
            const int R = wc * 64 + j * 16 + r;
            bvf[j] = *(const bf16x8*)&sm.g.Bs[cur][R * 32 + ((ks ^ ((R >> 1) & 3)) << 3)];
        }
#pragma unroll
        for (int i = 0; i < 2; i++)
#pragma unroll
            for (int j = 0; j < 4; j++)
                acc[i][j] = __builtin_amdgcn_mfma_f32_16x16x32_bf16(af[i], bvf[j], acc[i][j], 0, 0, 0);
        __syncthreads();
        cur ^= 1;
    }
#undef STAGE
    // ---- fused epilogue: band dots ----
    int colg[4]; float ub[4], vb[4];
#pragma unroll
    for (int j = 0; j < 4; j++) {
        colg[j] = n0 + wc * 64 + j * 16 + (lane & 15);
        ub[j] = u[colg[j]];
        vb[j] = v[colg[j]];
    }
    const int pslot = nt * 2 + wc;
#pragma unroll
    for (int i = 0; i < 2; i++) {
#pragma unroll
        for (int rr = 0; rr < 4; rr++) {
            const int row = m0 + wr * 32 + i * 16 + (lane >> 4) * 4 + rr;
            const int rm = (row == 0) ? 0 : row - 1;
            const int rp = (row == MM - 1) ? MM - 1 : row + 1;
            const __bf16* hm = A + (size_t)rm * DD;
            const __bf16* hz = A + (size_t)row * DD;
            const __bf16* hp = A + (size_t)rp * DD;
            float dua = 0.f, dna = 0.f, wa = 0.f;
#pragma unroll
            for (int j = 0; j < 4; j++) {
                const float Rv = acc[i][j][rr] + ub[j];
                dua += Rv * (float)hm[colg[j]];
                dna += Rv * (float)hp[colg[j]];
                wa  += vb[j] * (float)hz[colg[j]];
            }
#pragma unroll
            for (int o = 1; o < 16; o <<= 1) {
                dua += __shfl_xor(dua, o);
                dna += __shfl_xor(dna, o);
                wa  += __shfl_xor(wa, o);
            }
            if ((lane & 15) == 0) {
                du_part[pslot * MM + row] = dua;
                dn_part[pslot * MM + row] = dna;
                w_part [pslot * MM + row] = wa;
            }
        }
    }
    // ---- arrive: release partials, count blocks ----
    __syncthreads();
    if (t == 0) {
        __threadfence();                       // release (wb L2, device scope)
        sh_old = atomicAdd(cnt, 1);
    }
    __syncthreads();
    const int oldv = sh_old;
    if (oldv < NBLK - BB) return;
    // ---- tail scan: this block handles batch b ----
    const int b = oldv - (NBLK - BB);
    __threadfence();                           // acquire (inv stale L1/L2)
    for (int x = t; x < SS; x += 256) {
        const int idx2 = b * SS + x;
        float d1 = 0.f, d2 = 0.f, d3 = 0.f;
#pragma unroll
        for (int p = 0; p < 12; p++) {
            d1 += du_part[p * MM + idx2];
            d2 += dn_part[p * MM + idx2];
            d3 += w_part [p * MM + idx2];
        }
        sm.s.du[x] = d1; sm.s.dn[x] = d2; sm.s.w[x] = d3;
    }
    __syncthreads();
    const float cb = cbp[0];
    float pu_r[8];
#pragma unroll
    for (int e = 0; e < 8; e++) {
        const int s = t * 8 + e;
        const int flg = fl_i[b * SS + s];
        const bool au = flg & 1, ad = flg & 2;
        float puv = 0.f, pdv = 0.f;
        if (au || ad) {
            const float eu = au ? (sm.s.du[s + 1] + sm.s.w[s + 1] + cb) * (1.0f / DD) : 0.f;
            const float ed = ad ? (sm.s.dn[s - 1] + sm.s.w[s - 1] + cb) * (1.0f / DD) : 0.f;
            float mx = au ? eu : ed;
            if (au && ad) mx = fmaxf(eu, ed);
            const float zu = au ? expf(eu - mx) : 0.f;
            const float zd = ad ? expf(ed - mx) : 0.f;
            const float iz = 1.f / (zu + zd);
            puv = zu * iz; pdv = zd * iz;
        }
        pu_r[e] = puv;
        sm.s.pd[s] = pdv;
    }
    __syncthreads();
    double L[8];
    double mysum = 0.0;
#pragma unroll
    for (int e = 0; e < 8; e++) {
        const int s = t * 8 + e;
        double Lv = 0.0;
        float nbv = 0.f;
        if (s < SS - 1) {
            nbv = sqrtf(pu_r[e] * sm.s.pd[s + 1] + 1e-9f);
            const float pr = prsup[b * SS + s];
            const float nsup = pr + (1.f - pr) * nbv;
            Lv = (double)log2f(nsup + 1e-9f);
        }
        nb[b * SS + s] = nbv;
        L[e] = Lv; mysum += Lv;
    }
    sm.s.warr[t] = mysum;
    __syncthreads();
    for (int o = 1; o < 256; o <<= 1) {
        double vv = 0.0;
        if (t >= o) vv = sm.s.warr[t - o];
        __syncthreads();
        if (t >= o) sm.s.warr[t] += vv;
        __syncthreads();
    }
    double run = sm.s.warr[t] - mysum;    // exclusive prefix across threads
#pragma unroll
    for (int e = 0; e < 8; e++) {
        P2[(size_t)b * SS + t * 8 + e] = run;
        run += L[e];
    }
}

// ============ K2: fused elementwise output (g and n), 8 elems/thread ============
__global__ __launch_bounds__(256) void out_kernel(const float* __restrict__ prior,
        const float* __restrict__ nb, const double* __restrict__ P2,
        float* __restrict__ gout, float* __restrict__ nout) {
    const size_t t8 = (size_t)blockIdx.x * 256 + threadIdx.x;
    const int b = (int)(t8 >> 19);                 // (t8*8) / (SS*SS)
    const size_t off = t8 << 3;                    // element base
    const size_t r = off & ((1u << 22) - 1);
    const int i  = (int)(r >> 11);                 // row
    const int k0 = (int)(r & 2047);                // col base
    const f32x4 p0 = *(const f32x4*)(prior + off);
    const f32x4 p1 = *(const f32x4*)(prior + off + 4);
    const double* Pb = P2 + ((size_t)b << 11);
    const double Pi = Pb[i];
    const float* nbb = nb + ((size_t)b << 11);
    f32x4 g0, g1, n0, n1;
#pragma unroll
    for (int c = 0; c < 8; c++) {
        const int k = k0 + c;
        const float pr = (c < 4) ? p0[c] : p1[c - 4];
        float vv = 3.16227766016838e-5f;           // sqrt(1e-9)
        if (k == i + 1)      vv = nbb[i];
        else if (k == i - 1) vv = nbb[k];
        const float nval = pr + (1.f - pr) * vv;
        float g;
        if (k == i) {
            g = nval;
        } else {
            const double Pk = Pb[k];
            const double dd = (k > i) ? (Pk - Pi) : (Pi - Pk);
            g = exp2f((float)dd) + 1e-9f;
        }
        if (c < 4) { g0[c] = g; n0[c] = nval; }
        else       { g1[c - 4] = g; n1[c - 4] = nval; }
    }
    *(f32x4*)(gout + off)     = g0;
    *(f32x4*)(gout + off + 4) = g1;
    *(f32x4*)(nout + off)     = n0;
    *(f32x4*)(nout + off + 4) = n1;
}

extern "C" void kernel_launch(void* const* d_in, const int* in_sizes, int n_in,
                              void* d_out, int out_size, void* d_ws, size_t ws_size,
                              hipStream_t stream) {
    const float* hs    = (const float*)d_in[0];
    const int*   att   = (const int*)d_in[1];
    const float* prior = (const float*)d_in[2];
    const float* ln_w  = (const float*)d_in[3];
    const float* ln_b  = (const float*)d_in[4];
    const float* wq    = (const float*)d_in[5];
    const float* bq    = (const float*)d_in[6];
    const float* wk    = (const float*)d_in[7];
    const float* bk    = (const float*)d_in[8];

    float* gout = (float*)d_out;                       // g first (return order)
    float* nout = gout + (size_t)BB * SS * SS;

    char* ws = (char*)d_ws;
    __bf16* h       = (__bf16*)(ws);                   // 12,582,912
    __bf16* G       = (__bf16*)(ws + 12582912);        //  1,179,648
    float*  u       = (float*) (ws + 13762560);        //      3,072
    float*  v       = (float*) (ws + 13765632);        //      3,072
    float*  cbp     = (float*) (ws + 13768704);        //        256
    int*    fl      = (int*)   (ws + 13768960);        //     32,768
    float*  prsup   = (float*) (ws + 13801728);        //     32,768
    float*  du_part = (float*) (ws + 13834496);        //    393,216
    float*  dn_part = (float*) (ws + 14227712);        //    393,216
    float*  w_part  = (float*) (ws + 14620928);        //    393,216
    float*  nbuf    = (float*) (ws + 15014144);        //     32,768
    double* P2      = (double*)(ws + 15046912);        //     65,536
    int*    cnt     = (int*)   (ws + 15112448);        //        256

    combined_kernel<<<dim3(2609), dim3(256), 0, stream>>>(hs, ln_w, ln_b, wq, wk, bq, bk,
                                                          att, prior, G, u, v, cbp, h, fl, prsup, cnt);
    rgemm_kernel<<<dim3(NBLK), dim3(256), 0, stream>>>(h, G, u, v, du_part, dn_part, w_part,
                                                       cbp, fl, prsup, nbuf, P2, cnt);
    out_kernel<<<dim3((BB * SS * SS / 8) / 256), dim3(256), 0, stream>>>(prior, nbuf, P2, gout, nout);
}

// Round 11
// 117.074 us; speedup vs baseline: 1.0202x; 1.0202x over previous
//
#include <hip/hip_runtime.h>
#include <hip/hip_bf16.h>
#include <math.h>
#include <stdint.h>

#define BB 4
#define SS 2048
#define DD 768
#define MM (BB*SS)       // 8192
#define NBLK 768         // rgemm grid

typedef __attribute__((ext_vector_type(4))) float  f32x4;
typedef __attribute__((ext_vector_type(8))) __bf16 bf16x8;
typedef __attribute__((ext_vector_type(4))) __bf16 bf16x4;

#define AS1 __attribute__((address_space(1)))
#define AS3 __attribute__((address_space(3)))

// ============ K0: combined front kernel ============
// blocks [0,144):     G = Wq @ Wk^T, 64x64 tiles (12x12), fp32 reg-staged
// blocks [144,529):   u = Wq@bk (192), v = Wk@bq (192), cb = bq.bk (1)
// blocks [529,2577):  LayerNorm, 4 rows/block (wave per row)
// blocks [2577,2609): att-flag + prior-superdiag gather + cnt zero
__global__ __launch_bounds__(256) void combined_kernel(
        const float* __restrict__ x, const float* __restrict__ lw,
        const float* __restrict__ lb, const float* __restrict__ wq,
        const float* __restrict__ wk, const float* __restrict__ bq,
        const float* __restrict__ bk, const int* __restrict__ att,
        const float* __restrict__ prior, __bf16* __restrict__ G,
        float* __restrict__ u, float* __restrict__ v, float* __restrict__ cb,
        __bf16* __restrict__ h, int* __restrict__ fl, float* __restrict__ prsup,
        int* __restrict__ cnt) {
    __shared__ __attribute__((aligned(16))) __bf16 As[64][32];
    __shared__ __attribute__((aligned(16))) __bf16 Bs[64][32];
    const int bid = blockIdx.x;
    if (bid >= 2577) {
        // ---- gather ----
        const int idx = (bid - 2577) * 256 + threadIdx.x;   // 0..8191
        if (idx == 0) cnt[0] = 0;
        const int b = idx >> 11, s = idx & 2047;
        const bool au = (s < SS - 1) && ((att[((size_t)b * SS + s) * SS + (s + 1)] & 1) != 0);
        const bool ad = (s > 0)      && ((att[((size_t)b * SS + s) * SS + (s - 1)] & 1) != 0);
        fl[idx] = (au ? 1 : 0) | (ad ? 2 : 0);
        if (s < SS - 1)
            prsup[idx] = prior[((size_t)b * SS + s) * SS + s + 1];
        return;
    }
    if (bid >= 529) {
        // ---- LayerNorm ----
        const int row = (bid - 529) * 4 + (threadIdx.x >> 6);
        const int lane = threadIdx.x & 63;
        const float* xr = x + (size_t)row * DD + lane * 12;
        f32x4 a0 = *(const f32x4*)(xr), a1 = *(const f32x4*)(xr + 4), a2 = *(const f32x4*)(xr + 8);
        float xs[12];
#pragma unroll
        for (int c = 0; c < 4; c++) { xs[c] = a0[c]; xs[4 + c] = a1[c]; xs[8 + c] = a2[c]; }
        float s = 0.f, ss = 0.f;
#pragma unroll
        for (int c = 0; c < 12; c++) { s += xs[c]; ss += xs[c] * xs[c]; }
#pragma unroll
        for (int o = 1; o < 64; o <<= 1) { s += __shfl_xor(s, o); ss += __shfl_xor(ss, o); }
        const float mu = s * (1.0f / DD);
        const float var = ss * (1.0f / DD) - mu * mu;
        const float rstd = 1.0f / sqrtf(var + 1e-12f);
        const float* wp = lw + lane * 12; const float* bp = lb + lane * 12;
        f32x4 w0 = *(const f32x4*)(wp), w1 = *(const f32x4*)(wp + 4), w2 = *(const f32x4*)(wp + 8);
        f32x4 b0 = *(const f32x4*)(bp), b1 = *(const f32x4*)(bp + 4), b2 = *(const f32x4*)(bp + 8);
        bf16x4 o0, o1, o2;
#pragma unroll
        for (int c = 0; c < 4; c++) {
            o0[c] = (__bf16)((xs[c]     - mu) * rstd * w0[c] + b0[c]);
            o1[c] = (__bf16)((xs[4 + c] - mu) * rstd * w1[c] + b1[c]);
            o2[c] = (__bf16)((xs[8 + c] - mu) * rstd * w2[c] + b2[c]);
        }
        __bf16* hr = h + (size_t)row * DD + lane * 12;
        *(bf16x4*)(hr) = o0; *(bf16x4*)(hr + 4) = o1; *(bf16x4*)(hr + 8) = o2;
        return;
    }
    if (bid >= 144) {
        // ---- uvcb ----
        const int id = bid - 144;
        const int lane = threadIdx.x & 63, wv_ = threadIdx.x >> 6;
        if (id == 384) {
            if (wv_ != 0) return;
            float s = 0.f;
#pragma unroll
            for (int m = 0; m < 12; m++) s += bq[lane + 64 * m] * bk[lane + 64 * m];
#pragma unroll
            for (int o = 1; o < 64; o <<= 1) s += __shfl_xor(s, o);
            if (lane == 0) cb[0] = s;
            return;
        }
        const bool isU = id < 192;
        const int row = (isU ? id : id - 192) * 4 + wv_;
        const float* W = isU ? wq : wk;
        const float* bvec = isU ? bk : bq;
        const float* wr_ = W + (size_t)row * DD;
        float s = 0.f;
#pragma unroll
        for (int m = 0; m < 12; m++) s += wr_[lane + 64 * m] * bvec[lane + 64 * m];
#pragma unroll
        for (int o = 1; o < 64; o <<= 1) s += __shfl_xor(s, o);
        if (lane == 0) (isU ? u : v)[row] = s;
        return;
    }
    // ---- G-gemm: G[d,e] = sum_j wq[d,j] * wk[e,j], 64x64 tile ----
    const int m0 = (bid % 12) * 64;
    const int n0 = (bid / 12) * 64;
    const int t = threadIdx.x;
    const int wave = t >> 6, lane = t & 63;
    const int wr = wave >> 1, wc = wave & 1;
    const int srow = t >> 2, scol = (t & 3) * 8;    // 4 threads/row, 8 fp32 each
    f32x4 acc[2][2] = {};

    for (int k0 = 0; k0 < DD; k0 += 32) {
        const float* ga = wq + (size_t)(m0 + srow) * DD + k0 + scol;
        const float* gb = wk + (size_t)(n0 + srow) * DD + k0 + scol;
        f32x4 a0 = *(const f32x4*)(ga), a1 = *(const f32x4*)(ga + 4);
        f32x4 b0 = *(const f32x4*)(gb), b1 = *(const f32x4*)(gb + 4);
        bf16x8 av, bv;
#pragma unroll
        for (int c = 0; c < 4; c++) {
            av[c] = (__bf16)a0[c]; av[4 + c] = (__bf16)a1[c];
            bv[c] = (__bf16)b0[c]; bv[4 + c] = (__bf16)b1[c];
        }
        __syncthreads();
        *(bf16x8*)&As[srow][scol] = av;
        *(bf16x8*)&Bs[srow][scol] = bv;
        __syncthreads();
        const int r = lane & 15, ko = (lane >> 4) << 3;
        bf16x8 af[2], bvf[2];
#pragma unroll
        for (int i = 0; i < 2; i++) af[i]  = *(const bf16x8*)&As[wr * 32 + i * 16 + r][ko];
#pragma unroll
        for (int j = 0; j < 2; j++) bvf[j] = *(const bf16x8*)&Bs[wc * 32 + j * 16 + r][ko];
#pragma unroll
        for (int i = 0; i < 2; i++)
#pragma unroll
            for (int j = 0; j < 2; j++)
                acc[i][j] = __builtin_amdgcn_mfma_f32_16x16x32_bf16(af[i], bvf[j], acc[i][j], 0, 0, 0);
    }
#pragma unroll
    for (int i = 0; i < 2; i++) {
        const int mm = m0 + wr * 32 + i * 16 + (lane >> 4) * 4;
#pragma unroll
        for (int j = 0; j < 2; j++) {
            const int nn = n0 + wc * 32 + j * 16 + (lane & 15);
#pragma unroll
            for (int rr = 0; rr < 4; rr++)
                G[(size_t)(mm + rr) * DD + nn] = (__bf16)acc[i][j][rr];
        }
    }
}

// ============ K1: fused R-gemm + band dots + tail scan (26 KB LDS union) ============
// GEMM loop identical to R7 (single-buffer, slot-swizzle, 12 partial slots).
// After partials: release-fence + atomicAdd; the 4 blocks seeing old>=764
// acquire-fence and run the per-batch softmax/log2/double-prefix scan, staging
// only A=Σ(du+w), B=Σ(dn+w) (8KB+8KB) + pd (8KB) + warr (2KB) -> 26 KB union,
// preserving R7's 6-blocks/CU LDS occupancy (R9's 34 KB union was the harm).
__global__ __launch_bounds__(256) void rgemm_kernel(const __bf16* __restrict__ A,
        const __bf16* __restrict__ Bt, const float* __restrict__ u,
        const float* __restrict__ v, float* __restrict__ du_part,
        float* __restrict__ dn_part, float* __restrict__ w_part,
        const float* __restrict__ cbp, const int* __restrict__ fl_i,
        const float* __restrict__ prsup, float* __restrict__ nb,
        double* __restrict__ P2, int* __restrict__ cnt) {
    __shared__ __attribute__((aligned(16))) union {
        struct { __bf16 As[64 * 32]; __bf16 Bs[128 * 32]; } g;          // 12 KB
        struct { float A[SS]; float B[SS]; float pd[SS]; double warr[256]; } s; // 26 KB
    } sm;
    __shared__ int sh_old;
    const int bid = blockIdx.x;
    const int mt = bid & 127, nt = bid >> 7;
    const int m0 = mt * 64, n0 = nt * 128;
    const int t = threadIdx.x;
    const int wave = t >> 6, lane = t & 63;
    const int wr = wave >> 1, wc = wave & 1;
    f32x4 acc[2][4] = {};

    char* asb = (char*)sm.g.As;
    char* bsb = (char*)sm.g.Bs;
    const int rloc = lane >> 2;               // 0..15 row within wave-issue
    const int slot = lane & 3;                // 16B slot within 64B row
    const int rA = wave * 16 + rloc;          // tile-local row 0..63
    const int csw = (slot ^ ((rA >> 1) & 3)) << 3;   // swizzled element col

    for (int k0 = 0; k0 < DD; k0 += 32) {
        const __bf16* ga  = A  + (size_t)(m0 + rA) * DD + k0 + csw;
        const __bf16* gb0 = Bt + (size_t)(n0 + rA) * DD + k0 + csw;
        const __bf16* gb1 = gb0 + (size_t)64 * DD;
        __builtin_amdgcn_global_load_lds((const AS1 void*)(ga),  (AS3 void*)(asb + wave * 1024),        16, 0, 0);
        __builtin_amdgcn_global_load_lds((const AS1 void*)(gb0), (AS3 void*)(bsb + wave * 1024),        16, 0, 0);
        __builtin_amdgcn_global_load_lds((const AS1 void*)(gb1), (AS3 void*)(bsb + 4096 + wave * 1024), 16, 0, 0);
        __syncthreads();
        const int r = lane & 15, ks = lane >> 4;   // logical 16B slot 0..3
        bf16x8 af[2], bvf[4];
#pragma unroll
        for (int i = 0; i < 2; i++) {
            const int R = wr * 32 + i * 16 + r;
            af[i] = *(const bf16x8*)&sm.g.As[R * 32 + ((ks ^ ((R >> 1) & 3)) << 3)];
        }
#pragma unroll
        for (int j = 0; j < 4; j++) {
            const int R = wc * 64 + j * 16 + r;
            bvf[j] = *(const bf16x8*)&sm.g.Bs[R * 32 + ((ks ^ ((R >> 1) & 3)) << 3)];
        }
#pragma unroll
        for (int i = 0; i < 2; i++)
#pragma unroll
            for (int j = 0; j < 4; j++)
                acc[i][j] = __builtin_amdgcn_mfma_f32_16x16x32_bf16(af[i], bvf[j], acc[i][j], 0, 0, 0);
        __syncthreads();
    }
    // ---- fused epilogue: band dots ----
    int colg[4]; float ub[4], vb[4];
#pragma unroll
    for (int j = 0; j < 4; j++) {
        colg[j] = n0 + wc * 64 + j * 16 + (lane & 15);
        ub[j] = u[colg[j]];
        vb[j] = v[colg[j]];
    }
    const int pslot = nt * 2 + wc;
#pragma unroll
    for (int i = 0; i < 2; i++) {
#pragma unroll
        for (int rr = 0; rr < 4; rr++) {
            const int row = m0 + wr * 32 + i * 16 + (lane >> 4) * 4 + rr;
            const int rm = (row == 0) ? 0 : row - 1;
            const int rp = (row == MM - 1) ? MM - 1 : row + 1;
            const __bf16* hm = A + (size_t)rm * DD;
            const __bf16* hz = A + (size_t)row * DD;
            const __bf16* hp = A + (size_t)rp * DD;
            float dua = 0.f, dna = 0.f, wa = 0.f;
#pragma unroll
            for (int j = 0; j < 4; j++) {
                const float Rv = acc[i][j][rr] + ub[j];
                dua += Rv * (float)hm[colg[j]];
                dna += Rv * (float)hp[colg[j]];
                wa  += vb[j] * (float)hz[colg[j]];
            }
#pragma unroll
            for (int o = 1; o < 16; o <<= 1) {
                dua += __shfl_xor(dua, o);
                dna += __shfl_xor(dna, o);
                wa  += __shfl_xor(wa, o);
            }
            if ((lane & 15) == 0) {
                du_part[pslot * MM + row] = dua;
                dn_part[pslot * MM + row] = dna;
                w_part [pslot * MM + row] = wa;
            }
        }
    }
    // ---- arrive: release partials, count blocks ----
    __syncthreads();                           // all waves' stores vmcnt-drained
    if (t == 0) {
        __threadfence();                       // release: wb this XCD's L2
        sh_old = atomicAdd(cnt, 1);
    }
    __syncthreads();
    const int oldv = sh_old;
    if (oldv < NBLK - BB) return;
    // ---- tail scan: this block handles batch b ----
    const int b = oldv - (NBLK - BB);
    __threadfence();                           // acquire
    for (int x = t; x < SS; x += 256) {
        const int idx2 = b * SS + x;
        float d1 = 0.f, d2 = 0.f, d3 = 0.f;
#pragma unroll
        for (int p = 0; p < 12; p++) {
            d1 += du_part[p * MM + idx2];
            d2 += dn_part[p * MM + idx2];
            d3 += w_part [p * MM + idx2];
        }
        sm.s.A[x] = d1 + d3;                   // du_sum + w_sum
        sm.s.B[x] = d2 + d3;                   // dn_sum + w_sum
    }
    __syncthreads();
    const float cb = cbp[0];
    float pu_r[8];
#pragma unroll
    for (int e = 0; e < 8; e++) {
        const int s = t * 8 + e;
        const int flg = fl_i[b * SS + s];
        const bool au = flg & 1, ad = flg & 2;
        float puv = 0.f, pdv = 0.f;
        if (au || ad) {
            const float eu = au ? (sm.s.A[s + 1] + cb) * (1.0f / DD) : 0.f;
            const float ed = ad ? (sm.s.B[s - 1] + cb) * (1.0f / DD) : 0.f;
            float mx = au ? eu : ed;
            if (au && ad) mx = fmaxf(eu, ed);
            const float zu = au ? expf(eu - mx) : 0.f;
            const float zd = ad ? expf(ed - mx) : 0.f;
            const float iz = 1.f / (zu + zd);
            puv = zu * iz; pdv = zd * iz;
        }
        pu_r[e] = puv;
        sm.s.pd[s] = pdv;
    }
    __syncthreads();
    double L[8];
    double mysum = 0.0;
#pragma unroll
    for (int e = 0; e < 8; e++) {
        const int s = t * 8 + e;
        double Lv = 0.0;
        float nbv = 0.f;
        if (s < SS - 1) {
            nbv = sqrtf(pu_r[e] * sm.s.pd[s + 1] + 1e-9f);
            const float pr = prsup[b * SS + s];
            const float nsup = pr + (1.f - pr) * nbv;
            Lv = (double)log2f(nsup + 1e-9f);
        }
        nb[b * SS + s] = nbv;
        L[e] = Lv; mysum += Lv;
    }
    sm.s.warr[t] = mysum;
    __syncthreads();
    for (int o = 1; o < 256; o <<= 1) {
        double vv = 0.0;
        if (t >= o) vv = sm.s.warr[t - o];
        __syncthreads();
        if (t >= o) sm.s.warr[t] += vv;
        __syncthreads();
    }
    double run = sm.s.warr[t] - mysum;    // exclusive prefix across threads
#pragma unroll
    for (int e = 0; e < 8; e++) {
        P2[(size_t)b * SS + t * 8 + e] = run;
        run += L[e];
    }
}

// ============ K2: fused elementwise output (g and n), 8 elems/thread ============
__global__ __launch_bounds__(256) void out_kernel(const float* __restrict__ prior,
        const float* __restrict__ nb, const double* __restrict__ P2,
        float* __restrict__ gout, float* __restrict__ nout) {
    const size_t t8 = (size_t)blockIdx.x * 256 + threadIdx.x;
    const int b = (int)(t8 >> 19);                 // (t8*8) / (SS*SS)
    const size_t off = t8 << 3;                    // element base
    const size_t r = off & ((1u << 22) - 1);
    const int i  = (int)(r >> 11);                 // row
    const int k0 = (int)(r & 2047);                // col base
    const f32x4 p0 = *(const f32x4*)(prior + off);
    const f32x4 p1 = *(const f32x4*)(prior + off + 4);
    const double* Pb = P2 + ((size_t)b << 11);
    const double Pi = Pb[i];
    const float* nbb = nb + ((size_t)b << 11);
    f32x4 g0, g1, n0, n1;
#pragma unroll
    for (int c = 0; c < 8; c++) {
        const int k = k0 + c;
        const float pr = (c < 4) ? p0[c] : p1[c - 4];
        float vv = 3.16227766016838e-5f;           // sqrt(1e-9)
        if (k == i + 1)      vv = nbb[i];
        else if (k == i - 1) vv = nbb[k];
        const float nval = pr + (1.f - pr) * vv;
        float g;
        if (k == i) {
            g = nval;
        } else {
            const double Pk = Pb[k];
            const double dd = (k > i) ? (Pk - Pi) : (Pi - Pk);
            g = exp2f((float)dd) + 1e-9f;
        }
        if (c < 4) { g0[c] = g; n0[c] = nval; }
        else       { g1[c - 4] = g; n1[c - 4] = nval; }
    }
    *(f32x4*)(gout + off)     = g0;
    *(f32x4*)(gout + off + 4) = g1;
    *(f32x4*)(nout + off)     = n0;
    *(f32x4*)(nout + off + 4) = n1;
}

extern "C" void kernel_launch(void* const* d_in, const int* in_sizes, int n_in,
                              void* d_out, int out_size, void* d_ws, size_t ws_size,
                              hipStream_t stream) {
    const float* hs    = (const float*)d_in[0];
    const int*   att   = (const int*)d_in[1];
    const float* prior = (const float*)d_in[2];
    const float* ln_w  = (const float*)d_in[3];
    const float* ln_b  = (const float*)d_in[4];
    const float* wq    = (const float*)d_in[5];
    const float* bq    = (const float*)d_in[6];
    const float* wk    = (const float*)d_in[7];
    const float* bk    = (const float*)d_in[8];

    float* gout = (float*)d_out;                       // g first (return order)
    float* nout = gout + (size_t)BB * SS * SS;

    char* ws = (char*)d_ws;
    __bf16* h       = (__bf16*)(ws);                   // 12,582,912
    __bf16* G       = (__bf16*)(ws + 12582912);        //  1,179,648
    float*  u       = (float*) (ws + 13762560);        //      3,072
    float*  v       = (float*) (ws + 13765632);        //      3,072
    float*  cbp     = (float*) (ws + 13768704);        //        256
    int*    fl      = (int*)   (ws + 13768960);        //     32,768
    float*  prsup   = (float*) (ws + 13801728);        //     32,768
    float*  du_part = (float*) (ws + 13834496);        //    393,216
    float*  dn_part = (float*) (ws + 14227712);        //    393,216
    float*  w_part  = (float*) (ws + 14620928);        //    393,216
    float*  nbuf    = (float*) (ws + 15014144);        //     32,768
    double* P2      = (double*)(ws + 15046912);        //     65,536
    int*    cnt     = (int*)   (ws + 15112448);        //        256

    combined_kernel<<<dim3(2609), dim3(256), 0, stream>>>(hs, ln_w, ln_b, wq, wk, bq, bk,
                                                          att, prior, G, u, v, cbp, h, fl, prsup, cnt);
    rgemm_kernel<<<dim3(NBLK), dim3(256), 0, stream>>>(h, G, u, v, du_part, dn_part, w_part,
                                                       cbp, fl, prsup, nbuf, P2, cnt);
    out_kernel<<<dim3((BB * SS * SS / 8) / 256), dim3(256), 0, stream>>>(prior, nbuf, P2, gout, nout);
}

// Round 12
// 112.202 us; speedup vs baseline: 1.0645x; 1.0434x over previous
//
#include <hip/hip_runtime.h>
#include <hip/hip_bf16.h>
#include <math.h>
#include <stdint.h>

#define BB 4
#define SS 2048
#define DD 768
#define MM (BB*SS)       // 8192

typedef __attribute__((ext_vector_type(4))) float  f32x4;
typedef __attribute__((ext_vector_type(8))) __bf16 bf16x8;
typedef __attribute__((ext_vector_type(4))) __bf16 bf16x4;

#define AS1 __attribute__((address_space(1)))
#define AS3 __attribute__((address_space(3)))

// ============ K0: combined front kernel ============
// blocks [0,144):     G = Wq @ Wk^T, 64x64 tiles (12x12), fp32 reg-staged
// blocks [144,529):   u = Wq@bk (192), v = Wk@bq (192), cb = bq.bk (1)
// blocks [529,2577):  LayerNorm, 4 rows/block (wave per row)
// blocks [2577,2609): att-flag + prior-superdiagonal gather (1 row/thread)
__global__ __launch_bounds__(256) void combined_kernel(
        const float* __restrict__ x, const float* __restrict__ lw,
        const float* __restrict__ lb, const float* __restrict__ wq,
        const float* __restrict__ wk, const float* __restrict__ bq,
        const float* __restrict__ bk, const int* __restrict__ att,
        const float* __restrict__ prior, __bf16* __restrict__ G,
        float* __restrict__ u, float* __restrict__ v, float* __restrict__ cb,
        __bf16* __restrict__ h, int* __restrict__ fl, float* __restrict__ prsup) {
    __shared__ __attribute__((aligned(16))) __bf16 As[64][32];
    __shared__ __attribute__((aligned(16))) __bf16 Bs[64][32];
    const int bid = blockIdx.x;
    if (bid >= 2577) {
        // ---- gather ----
        const int idx = (bid - 2577) * 256 + threadIdx.x;   // 0..8191
        const int b = idx >> 11, s = idx & 2047;
        const bool au = (s < SS - 1) && ((att[((size_t)b * SS + s) * SS + (s + 1)] & 1) != 0);
        const bool ad = (s > 0)      && ((att[((size_t)b * SS + s) * SS + (s - 1)] & 1) != 0);
        fl[idx] = (au ? 1 : 0) | (ad ? 2 : 0);
        if (s < SS - 1)
            prsup[idx] = prior[((size_t)b * SS + s) * SS + s + 1];
        return;
    }
    if (bid >= 529) {
        // ---- LayerNorm ----
        const int row = (bid - 529) * 4 + (threadIdx.x >> 6);
        const int lane = threadIdx.x & 63;
        const float* xr = x + (size_t)row * DD + lane * 12;
        f32x4 a0 = *(const f32x4*)(xr), a1 = *(const f32x4*)(xr + 4), a2 = *(const f32x4*)(xr + 8);
        float xs[12];
#pragma unroll
        for (int c = 0; c < 4; c++) { xs[c] = a0[c]; xs[4 + c] = a1[c]; xs[8 + c] = a2[c]; }
        float s = 0.f, ss = 0.f;
#pragma unroll
        for (int c = 0; c < 12; c++) { s += xs[c]; ss += xs[c] * xs[c]; }
#pragma unroll
        for (int o = 1; o < 64; o <<= 1) { s += __shfl_xor(s, o); ss += __shfl_xor(ss, o); }
        const float mu = s * (1.0f / DD);
        const float var = ss * (1.0f / DD) - mu * mu;
        const float rstd = 1.0f / sqrtf(var + 1e-12f);
        const float* wp = lw + lane * 12; const float* bp = lb + lane * 12;
        f32x4 w0 = *(const f32x4*)(wp), w1 = *(const f32x4*)(wp + 4), w2 = *(const f32x4*)(wp + 8);
        f32x4 b0 = *(const f32x4*)(bp), b1 = *(const f32x4*)(bp + 4), b2 = *(const f32x4*)(bp + 8);
        bf16x4 o0, o1, o2;
#pragma unroll
        for (int c = 0; c < 4; c++) {
            o0[c] = (__bf16)((xs[c]     - mu) * rstd * w0[c] + b0[c]);
            o1[c] = (__bf16)((xs[4 + c] - mu) * rstd * w1[c] + b1[c]);
            o2[c] = (__bf16)((xs[8 + c] - mu) * rstd * w2[c] + b2[c]);
        }
        __bf16* hr = h + (size_t)row * DD + lane * 12;
        *(bf16x4*)(hr) = o0; *(bf16x4*)(hr + 4) = o1; *(bf16x4*)(hr + 8) = o2;
        return;
    }
    if (bid >= 144) {
        // ---- uvcb ----
        const int id = bid - 144;
        const int lane = threadIdx.x & 63, wv_ = threadIdx.x >> 6;
        if (id == 384) {
            if (wv_ != 0) return;
            float s = 0.f;
#pragma unroll
            for (int m = 0; m < 12; m++) s += bq[lane + 64 * m] * bk[lane + 64 * m];
#pragma unroll
            for (int o = 1; o < 64; o <<= 1) s += __shfl_xor(s, o);
            if (lane == 0) cb[0] = s;
            return;
        }
        const bool isU = id < 192;
        const int row = (isU ? id : id - 192) * 4 + wv_;
        const float* W = isU ? wq : wk;
        const float* bvec = isU ? bk : bq;
        const float* wr_ = W + (size_t)row * DD;
        float s = 0.f;
#pragma unroll
        for (int m = 0; m < 12; m++) s += wr_[lane + 64 * m] * bvec[lane + 64 * m];
#pragma unroll
        for (int o = 1; o < 64; o <<= 1) s += __shfl_xor(s, o);
        if (lane == 0) (isU ? u : v)[row] = s;
        return;
    }
    // ---- G-gemm: G[d,e] = sum_j wq[d,j] * wk[e,j], 64x64 tile ----
    const int m0 = (bid % 12) * 64;
    const int n0 = (bid / 12) * 64;
    const int t = threadIdx.x;
    const int wave = t >> 6, lane = t & 63;
    const int wr = wave >> 1, wc = wave & 1;
    const int srow = t >> 2, scol = (t & 3) * 8;    // 4 threads/row, 8 fp32 each
    f32x4 acc[2][2] = {};

    for (int k0 = 0; k0 < DD; k0 += 32) {
        const float* ga = wq + (size_t)(m0 + srow) * DD + k0 + scol;
        const float* gb = wk + (size_t)(n0 + srow) * DD + k0 + scol;
        f32x4 a0 = *(const f32x4*)(ga), a1 = *(const f32x4*)(ga + 4);
        f32x4 b0 = *(const f32x4*)(gb), b1 = *(const f32x4*)(gb + 4);
        bf16x8 av, bv;
#pragma unroll
        for (int c = 0; c < 4; c++) {
            av[c] = (__bf16)a0[c]; av[4 + c] = (__bf16)a1[c];
            bv[c] = (__bf16)b0[c]; bv[4 + c] = (__bf16)b1[c];
        }
        __syncthreads();
        *(bf16x8*)&As[srow][scol] = av;
        *(bf16x8*)&Bs[srow][scol] = bv;
        __syncthreads();
        const int r = lane & 15, ko = (lane >> 4) << 3;
        bf16x8 af[2], bvf[2];
#pragma unroll
        for (int i = 0; i < 2; i++) af[i]  = *(const bf16x8*)&As[wr * 32 + i * 16 + r][ko];
#pragma unroll
        for (int j = 0; j < 2; j++) bvf[j] = *(const bf16x8*)&Bs[wc * 32 + j * 16 + r][ko];
#pragma unroll
        for (int i = 0; i < 2; i++)
#pragma unroll
            for (int j = 0; j < 2; j++)
                acc[i][j] = __builtin_amdgcn_mfma_f32_16x16x32_bf16(af[i], bvf[j], acc[i][j], 0, 0, 0);
    }
#pragma unroll
    for (int i = 0; i < 2; i++) {
        const int mm = m0 + wr * 32 + i * 16 + (lane >> 4) * 4;
#pragma unroll
        for (int j = 0; j < 2; j++) {
            const int nn = n0 + wc * 32 + j * 16 + (lane & 15);
#pragma unroll
            for (int rr = 0; rr < 4; rr++)
                G[(size_t)(mm + rr) * DD + nn] = (__bf16)acc[i][j][rr];
        }
    }
}

// ============ K1: fused R-gemm + band dots (BK=32, slot-swizzled LDS) ============
__global__ __launch_bounds__(256) void rgemm_kernel(const __bf16* __restrict__ A,
        const __bf16* __restrict__ Bt, const float* __restrict__ u,
        const float* __restrict__ v, float* __restrict__ du_part,
        float* __restrict__ dn_part, float* __restrict__ w_part) {
    __shared__ __attribute__((aligned(16))) __bf16 As[64 * 32];
    __shared__ __attribute__((aligned(16))) __bf16 Bs[128 * 32];
    const int bid = blockIdx.x;
    const int mt = bid & 127, nt = bid >> 7;
    const int m0 = mt * 64, n0 = nt * 128;
    const int t = threadIdx.x;
    const int wave = t >> 6, lane = t & 63;
    const int wr = wave >> 1, wc = wave & 1;
    f32x4 acc[2][4] = {};

    char* asb = (char*)As;
    char* bsb = (char*)Bs;
    const int rloc = lane >> 2;               // 0..15 row within wave-issue
    const int slot = lane & 3;                // 16B slot within 64B row
    const int rA = wave * 16 + rloc;          // tile-local row 0..63
    const int csw = (slot ^ ((rA >> 1) & 3)) << 3;   // swizzled element col

    for (int k0 = 0; k0 < DD; k0 += 32) {
        const __bf16* ga  = A  + (size_t)(m0 + rA) * DD + k0 + csw;
        const __bf16* gb0 = Bt + (size_t)(n0 + rA) * DD + k0 + csw;
        const __bf16* gb1 = gb0 + (size_t)64 * DD;
        __builtin_amdgcn_global_load_lds((const AS1 void*)(ga),  (AS3 void*)(asb + wave * 1024),        16, 0, 0);
        __builtin_amdgcn_global_load_lds((const AS1 void*)(gb0), (AS3 void*)(bsb + wave * 1024),        16, 0, 0);
        __builtin_amdgcn_global_load_lds((const AS1 void*)(gb1), (AS3 void*)(bsb + 4096 + wave * 1024), 16, 0, 0);
        __syncthreads();
        const int r = lane & 15, ks = lane >> 4;   // logical 16B slot 0..3
        bf16x8 af[2], bvf[4];
#pragma unroll
        for (int i = 0; i < 2; i++) {
            const int R = wr * 32 + i * 16 + r;
            af[i] = *(const bf16x8*)&As[R * 32 + ((ks ^ ((R >> 1) & 3)) << 3)];
        }
#pragma unroll
        for (int j = 0; j < 4; j++) {
            const int R = wc * 64 + j * 16 + r;
            bvf[j] = *(const bf16x8*)&Bs[R * 32 + ((ks ^ ((R >> 1) & 3)) << 3)];
        }
#pragma unroll
        for (int i = 0; i < 2; i++)
#pragma unroll
            for (int j = 0; j < 4; j++)
                acc[i][j] = __builtin_amdgcn_mfma_f32_16x16x32_bf16(af[i], bvf[j], acc[i][j], 0, 0, 0);
        __syncthreads();
    }
    // ---- fused epilogue: band dots ----
    int colg[4]; float ub[4], vb[4];
#pragma unroll
    for (int j = 0; j < 4; j++) {
        colg[j] = n0 + wc * 64 + j * 16 + (lane & 15);
        ub[j] = u[colg[j]];
        vb[j] = v[colg[j]];
    }
    const int pslot = nt * 2 + wc;
#pragma unroll
    for (int i = 0; i < 2; i++) {
#pragma unroll
        for (int rr = 0; rr < 4; rr++) {
            const int row = m0 + wr * 32 + i * 16 + (lane >> 4) * 4 + rr;
            const int rm = (row == 0) ? 0 : row - 1;
            const int rp = (row == MM - 1) ? MM - 1 : row + 1;
            const __bf16* hm = A + (size_t)rm * DD;
            const __bf16* hz = A + (size_t)row * DD;
            const __bf16* hp = A + (size_t)rp * DD;
            float dua = 0.f, dna = 0.f, wa = 0.f;
#pragma unroll
            for (int j = 0; j < 4; j++) {
                const float Rv = acc[i][j][rr] + ub[j];
                dua += Rv * (float)hm[colg[j]];
                dna += Rv * (float)hp[colg[j]];
                wa  += vb[j] * (float)hz[colg[j]];
            }
#pragma unroll
            for (int o = 1; o < 16; o <<= 1) {
                dua += __shfl_xor(dua, o);
                dna += __shfl_xor(dna, o);
                wa  += __shfl_xor(wa, o);
            }
            if ((lane & 15) == 0) {
                du_part[pslot * MM + row] = dua;
                dn_part[pslot * MM + row] = dna;
                w_part [pslot * MM + row] = wa;
            }
        }
    }
}

// ============ K2: per-batch assemble, softmax, nb, log2, double prefix scan ============
__global__ __launch_bounds__(256) void scan_kernel(const float* __restrict__ du_part,
        const float* __restrict__ dn_part, const float* __restrict__ w_part,
        const float* __restrict__ cbp, const int* __restrict__ fl_i,
        const float* __restrict__ prsup,
        float* __restrict__ nb, double* __restrict__ P2) {
    const int b = blockIdx.x;
    const int t = threadIdx.x;
    __shared__ float du_s[SS], dn_s[SS], w_s[SS], sh_pd[SS];
    __shared__ double warr[256];
    for (int x = t; x < SS; x += 256) {
        const int idx = b * SS + x;
        float d1 = 0.f, d2 = 0.f, d3 = 0.f;
#pragma unroll
        for (int p = 0; p < 12; p++) {
            d1 += du_part[p * MM + idx];
            d2 += dn_part[p * MM + idx];
            d3 += w_part [p * MM + idx];
        }
        du_s[x] = d1; dn_s[x] = d2; w_s[x] = d3;
    }
    __syncthreads();
    const float cb = cbp[0];
    float pu_r[8];
#pragma unroll
    for (int e = 0; e < 8; e++) {
        const int s = t * 8 + e;
        const int fl = fl_i[b * SS + s];
        const bool au = fl & 1, ad = fl & 2;
        float puv = 0.f, pdv = 0.f;
        if (au || ad) {
            const float eu = au ? (du_s[s + 1] + w_s[s + 1] + cb) * (1.0f / DD) : 0.f;
            const float ed = ad ? (dn_s[s - 1] + w_s[s - 1] + cb) * (1.0f / DD) : 0.f;
            float mx = au ? eu : ed;
            if (au && ad) mx = fmaxf(eu, ed);
            const float zu = au ? expf(eu - mx) : 0.f;
            const float zd = ad ? expf(ed - mx) : 0.f;
            const float iz = 1.f / (zu + zd);
            puv = zu * iz; pdv = zd * iz;
        }
        pu_r[e] = puv;
        sh_pd[s] = pdv;
    }
    __syncthreads();
    double L[8];
    double mysum = 0.0;
#pragma unroll
    for (int e = 0; e < 8; e++) {
        const int s = t * 8 + e;
        double Lv = 0.0;
        float nbv = 0.f;
        if (s < SS - 1) {
            nbv = sqrtf(pu_r[e] * sh_pd[s + 1] + 1e-9f);
            const float pr = prsup[b * SS + s];
            const float nsup = pr + (1.f - pr) * nbv;
            Lv = (double)log2f(nsup + 1e-9f);
        }
        nb[b * SS + s] = nbv;
        L[e] = Lv; mysum += Lv;
    }
    warr[t] = mysum;
    __syncthreads();
    for (int o = 1; o < 256; o <<= 1) {
        double vv = 0.0;
        if (t >= o) vv = warr[t - o];
        __syncthreads();
        if (t >= o) warr[t] += vv;
        __syncthreads();
    }
    double run = warr[t] - mysum;    // exclusive prefix across threads
#pragma unroll
    for (int e = 0; e < 8; e++) {
        P2[(size_t)b * SS + t * 8 + e] = run;
        run += L[e];
    }
}

// ============ K3: fused elementwise output, 8 elems/thread, nontemporal ============
__global__ __launch_bounds__(256) void out_kernel(const float* __restrict__ prior,
        const float* __restrict__ nb, const double* __restrict__ P2,
        float* __restrict__ gout, float* __restrict__ nout) {
    const size_t t8 = (size_t)blockIdx.x * 256 + threadIdx.x;
    const int b = (int)(t8 >> 19);                 // (t8*8) / (SS*SS)
    const size_t off = t8 << 3;                    // element base
    const size_t r = off & ((1u << 22) - 1);
    const int i  = (int)(r >> 11);                 // row
    const int k0 = (int)(r & 2047);                // col base
    const f32x4 p0 = __builtin_nontemporal_load((const f32x4*)(prior + off));
    const f32x4 p1 = __builtin_nontemporal_load((const f32x4*)(prior + off + 4));
    const double* Pb = P2 + ((size_t)b << 11);
    const double Pi = Pb[i];
    const float* nbb = nb + ((size_t)b << 11);
    f32x4 g0, g1, n0, n1;
#pragma unroll
    for (int c = 0; c < 8; c++) {
        const int k = k0 + c;
        const float pr = (c < 4) ? p0[c] : p1[c - 4];
        float vv = 3.16227766016838e-5f;           // sqrt(1e-9)
        if (k == i + 1)      vv = nbb[i];
        else if (k == i - 1) vv = nbb[k];
        const float nval = pr + (1.f - pr) * vv;
        float g;
        if (k == i) {
            g = nval;
        } else {
            const double Pk = Pb[k];
            const double dd = (k > i) ? (Pk - Pi) : (Pi - Pk);
            g = exp2f((float)dd) + 1e-9f;
        }
        if (c < 4) { g0[c] = g; n0[c] = nval; }
        else       { g1[c - 4] = g; n1[c - 4] = nval; }
    }
    __builtin_nontemporal_store(g0, (f32x4*)(gout + off));
    __builtin_nontemporal_store(g1, (f32x4*)(gout + off + 4));
    __builtin_nontemporal_store(n0, (f32x4*)(nout + off));
    __builtin_nontemporal_store(n1, (f32x4*)(nout + off + 4));
}

extern "C" void kernel_launch(void* const* d_in, const int* in_sizes, int n_in,
                              void* d_out, int out_size, void* d_ws, size_t ws_size,
                              hipStream_t stream) {
    const float* hs    = (const float*)d_in[0];
    const int*   att   = (const int*)d_in[1];
    const float* prior = (const float*)d_in[2];
    const float* ln_w  = (const float*)d_in[3];
    const float* ln_b  = (const float*)d_in[4];
    const float* wq    = (const float*)d_in[5];
    const float* bq    = (const float*)d_in[6];
    const float* wk    = (const float*)d_in[7];
    const float* bk    = (const float*)d_in[8];

    float* gout = (float*)d_out;                       // g first (return order)
    float* nout = gout + (size_t)BB * SS * SS;

    char* ws = (char*)d_ws;
    __bf16* h       = (__bf16*)(ws);                   // 12,582,912
    __bf16* G       = (__bf16*)(ws + 12582912);        //  1,179,648
    float*  u       = (float*) (ws + 13762560);        //      3,072
    float*  v       = (float*) (ws + 13765632);        //      3,072
    float*  cbp     = (float*) (ws + 13768704);        //        256
    int*    fl      = (int*)   (ws + 13768960);        //     32,768
    float*  prsup   = (float*) (ws + 13801728);        //     32,768
    float*  du_part = (float*) (ws + 13834496);        //    393,216
    float*  dn_part = (float*) (ws + 14227712);        //    393,216
    float*  w_part  = (float*) (ws + 14620928);        //    393,216
    float*  nbuf    = (float*) (ws + 15014144);        //     32,768
    double* P2      = (double*)(ws + 15046912);        //     65,536

    combined_kernel<<<dim3(2609), dim3(256), 0, stream>>>(hs, ln_w, ln_b, wq, wk, bq, bk,
                                                          att, prior, G, u, v, cbp, h, fl, prsup);
    rgemm_kernel<<<dim3(768), dim3(256), 0, stream>>>(h, G, u, v, du_part, dn_part, w_part);
    scan_kernel<<<dim3(BB), dim3(256), 0, stream>>>(du_part, dn_part, w_part, cbp, fl, prsup, nbuf, P2);
    out_kernel<<<dim3((BB * SS * SS / 8) / 256), dim3(256), 0, stream>>>(prior, nbuf, P2, gout, nout);
}

// Round 13
// 97.746 us; speedup vs baseline: 1.2220x; 1.1479x over previous
//
#include <hip/hip_runtime.h>
#include <hip/hip_bf16.h>
#include <math.h>
#include <stdint.h>

#define BB 4
#define SS 2048
#define DD 768
#define MM (BB*SS)       // 8192

typedef __attribute__((ext_vector_type(4))) float  f32x4;
typedef __attribute__((ext_vector_type(8))) __bf16 bf16x8;
typedef __attribute__((ext_vector_type(4))) __bf16 bf16x4;

#define AS1 __attribute__((address_space(1)))
#define AS3 __attribute__((address_space(3)))

// ============ K0: combined front kernel ============
// blocks [0,144):     G = Wq @ Wk^T, 64x64 tiles (12x12), fp32 reg-staged
// blocks [144,529):   u = Wq@bk (192), v = Wk@bq (192), cb = bq.bk (1)
// blocks [529,2577):  LayerNorm, 4 rows/block (wave per row)
// blocks [2577,2609): att-flag + prior-superdiag gather + zero du/dn/w accumulators
__global__ __launch_bounds__(256) void combined_kernel(
        const float* __restrict__ x, const float* __restrict__ lw,
        const float* __restrict__ lb, const float* __restrict__ wq,
        const float* __restrict__ wk, const float* __restrict__ bq,
        const float* __restrict__ bk, const int* __restrict__ att,
        const float* __restrict__ prior, __bf16* __restrict__ G,
        float* __restrict__ u, float* __restrict__ v, float* __restrict__ cb,
        __bf16* __restrict__ h, int* __restrict__ fl, float* __restrict__ prsup,
        float* __restrict__ du_g, float* __restrict__ dn_g, float* __restrict__ w_g) {
    __shared__ __attribute__((aligned(16))) __bf16 As[64][32];
    __shared__ __attribute__((aligned(16))) __bf16 Bs[64][32];
    const int bid = blockIdx.x;
    if (bid >= 2577) {
        // ---- gather + accumulator zeroing ----
        const int idx = (bid - 2577) * 256 + threadIdx.x;   // 0..8191
        const int b = idx >> 11, s = idx & 2047;
        const bool au = (s < SS - 1) && ((att[((size_t)b * SS + s) * SS + (s + 1)] & 1) != 0);
        const bool ad = (s > 0)      && ((att[((size_t)b * SS + s) * SS + (s - 1)] & 1) != 0);
        fl[idx] = (au ? 1 : 0) | (ad ? 2 : 0);
        if (s < SS - 1)
            prsup[idx] = prior[((size_t)b * SS + s) * SS + s + 1];
        du_g[idx] = 0.f; dn_g[idx] = 0.f; w_g[idx] = 0.f;
        return;
    }
    if (bid >= 529) {
        // ---- LayerNorm ----
        const int row = (bid - 529) * 4 + (threadIdx.x >> 6);
        const int lane = threadIdx.x & 63;
        const float* xr = x + (size_t)row * DD + lane * 12;
        f32x4 a0 = *(const f32x4*)(xr), a1 = *(const f32x4*)(xr + 4), a2 = *(const f32x4*)(xr + 8);
        float xs[12];
#pragma unroll
        for (int c = 0; c < 4; c++) { xs[c] = a0[c]; xs[4 + c] = a1[c]; xs[8 + c] = a2[c]; }
        float s = 0.f, ss = 0.f;
#pragma unroll
        for (int c = 0; c < 12; c++) { s += xs[c]; ss += xs[c] * xs[c]; }
#pragma unroll
        for (int o = 1; o < 64; o <<= 1) { s += __shfl_xor(s, o); ss += __shfl_xor(ss, o); }
        const float mu = s * (1.0f / DD);
        const float var = ss * (1.0f / DD) - mu * mu;
        const float rstd = 1.0f / sqrtf(var + 1e-12f);
        const float* wp = lw + lane * 12; const float* bp = lb + lane * 12;
        f32x4 w0 = *(const f32x4*)(wp), w1 = *(const f32x4*)(wp + 4), w2 = *(const f32x4*)(wp + 8);
        f32x4 b0 = *(const f32x4*)(bp), b1 = *(const f32x4*)(bp + 4), b2 = *(const f32x4*)(bp + 8);
        bf16x4 o0, o1, o2;
#pragma unroll
        for (int c = 0; c < 4; c++) {
            o0[c] = (__bf16)((xs[c]     - mu) * rstd * w0[c] + b0[c]);
            o1[c] = (__bf16)((xs[4 + c] - mu) * rstd * w1[c] + b1[c]);
            o2[c] = (__bf16)((xs[8 + c] - mu) * rstd * w2[c] + b2[c]);
        }
        __bf16* hr = h + (size_t)row * DD + lane * 12;
        *(bf16x4*)(hr) = o0; *(bf16x4*)(hr + 4) = o1; *(bf16x4*)(hr + 8) = o2;
        return;
    }
    if (bid >= 144) {
        // ---- uvcb ----
        const int id = bid - 144;
        const int lane = threadIdx.x & 63, wv_ = threadIdx.x >> 6;
        if (id == 384) {
            if (wv_ != 0) return;
            float s = 0.f;
#pragma unroll
            for (int m = 0; m < 12; m++) s += bq[lane + 64 * m] * bk[lane + 64 * m];
#pragma unroll
            for (int o = 1; o < 64; o <<= 1) s += __shfl_xor(s, o);
            if (lane == 0) cb[0] = s;
            return;
        }
        const bool isU = id < 192;
        const int row = (isU ? id : id - 192) * 4 + wv_;
        const float* W = isU ? wq : wk;
        const float* bvec = isU ? bk : bq;
        const float* wr_ = W + (size_t)row * DD;
        float s = 0.f;
#pragma unroll
        for (int m = 0; m < 12; m++) s += wr_[lane + 64 * m] * bvec[lane + 64 * m];
#pragma unroll
        for (int o = 1; o < 64; o <<= 1) s += __shfl_xor(s, o);
        if (lane == 0) (isU ? u : v)[row] = s;
        return;
    }
    // ---- G-gemm: G[d,e] = sum_j wq[d,j] * wk[e,j], 64x64 tile ----
    const int m0 = (bid % 12) * 64;
    const int n0 = (bid / 12) * 64;
    const int t = threadIdx.x;
    const int wave = t >> 6, lane = t & 63;
    const int wr = wave >> 1, wc = wave & 1;
    const int srow = t >> 2, scol = (t & 3) * 8;    // 4 threads/row, 8 fp32 each
    f32x4 acc[2][2] = {};

    for (int k0 = 0; k0 < DD; k0 += 32) {
        const float* ga = wq + (size_t)(m0 + srow) * DD + k0 + scol;
        const float* gb = wk + (size_t)(n0 + srow) * DD + k0 + scol;
        f32x4 a0 = *(const f32x4*)(ga), a1 = *(const f32x4*)(ga + 4);
        f32x4 b0 = *(const f32x4*)(gb), b1 = *(const f32x4*)(gb + 4);
        bf16x8 av, bv;
#pragma unroll
        for (int c = 0; c < 4; c++) {
            av[c] = (__bf16)a0[c]; av[4 + c] = (__bf16)a1[c];
            bv[c] = (__bf16)b0[c]; bv[4 + c] = (__bf16)b1[c];
        }
        __syncthreads();
        *(bf16x8*)&As[srow][scol] = av;
        *(bf16x8*)&Bs[srow][scol] = bv;
        __syncthreads();
        const int r = lane & 15, ko = (lane >> 4) << 3;
        bf16x8 af[2], bvf[2];
#pragma unroll
        for (int i = 0; i < 2; i++) af[i]  = *(const bf16x8*)&As[wr * 32 + i * 16 + r][ko];
#pragma unroll
        for (int j = 0; j < 2; j++) bvf[j] = *(const bf16x8*)&Bs[wc * 32 + j * 16 + r][ko];
#pragma unroll
        for (int i = 0; i < 2; i++)
#pragma unroll
            for (int j = 0; j < 2; j++)
                acc[i][j] = __builtin_amdgcn_mfma_f32_16x16x32_bf16(af[i], bvf[j], acc[i][j], 0, 0, 0);
    }
#pragma unroll
    for (int i = 0; i < 2; i++) {
        const int mm = m0 + wr * 32 + i * 16 + (lane >> 4) * 4;
#pragma unroll
        for (int j = 0; j < 2; j++) {
            const int nn = n0 + wc * 32 + j * 16 + (lane & 15);
#pragma unroll
            for (int rr = 0; rr < 4; rr++)
                G[(size_t)(mm + rr) * DD + nn] = (__bf16)acc[i][j][rr];
        }
    }
}

// ============ K1: fused R-gemm + band dots (BK=32, slot-swizzled LDS, atomic reduce) ============
__global__ __launch_bounds__(256) void rgemm_kernel(const __bf16* __restrict__ A,
        const __bf16* __restrict__ Bt, const float* __restrict__ u,
        const float* __restrict__ v, float* __restrict__ du_g,
        float* __restrict__ dn_g, float* __restrict__ w_g) {
    __shared__ __attribute__((aligned(16))) __bf16 As[64 * 32];
    __shared__ __attribute__((aligned(16))) __bf16 Bs[128 * 32];
    const int bid = blockIdx.x;
    const int mt = bid & 127, nt = bid >> 7;
    const int m0 = mt * 64, n0 = nt * 128;
    const int t = threadIdx.x;
    const int wave = t >> 6, lane = t & 63;
    const int wr = wave >> 1, wc = wave & 1;
    f32x4 acc[2][4] = {};

    char* asb = (char*)As;
    char* bsb = (char*)Bs;
    const int rloc = lane >> 2;               // 0..15 row within wave-issue
    const int slot = lane & 3;                // 16B slot within 64B row
    const int rA = wave * 16 + rloc;          // tile-local row 0..63
    const int csw = (slot ^ ((rA >> 1) & 3)) << 3;   // swizzled element col

    for (int k0 = 0; k0 < DD; k0 += 32) {
        const __bf16* ga  = A  + (size_t)(m0 + rA) * DD + k0 + csw;
        const __bf16* gb0 = Bt + (size_t)(n0 + rA) * DD + k0 + csw;
        const __bf16* gb1 = gb0 + (size_t)64 * DD;
        __builtin_amdgcn_global_load_lds((const AS1 void*)(ga),  (AS3 void*)(asb + wave * 1024),        16, 0, 0);
        __builtin_amdgcn_global_load_lds((const AS1 void*)(gb0), (AS3 void*)(bsb + wave * 1024),        16, 0, 0);
        __builtin_amdgcn_global_load_lds((const AS1 void*)(gb1), (AS3 void*)(bsb + 4096 + wave * 1024), 16, 0, 0);
        __syncthreads();
        const int r = lane & 15, ks = lane >> 4;   // logical 16B slot 0..3
        bf16x8 af[2], bvf[4];
#pragma unroll
        for (int i = 0; i < 2; i++) {
            const int R = wr * 32 + i * 16 + r;
            af[i] = *(const bf16x8*)&As[R * 32 + ((ks ^ ((R >> 1) & 3)) << 3)];
        }
#pragma unroll
        for (int j = 0; j < 4; j++) {
            const int R = wc * 64 + j * 16 + r;
            bvf[j] = *(const bf16x8*)&Bs[R * 32 + ((ks ^ ((R >> 1) & 3)) << 3)];
        }
#pragma unroll
        for (int i = 0; i < 2; i++)
#pragma unroll
            for (int j = 0; j < 4; j++)
                acc[i][j] = __builtin_amdgcn_mfma_f32_16x16x32_bf16(af[i], bvf[j], acc[i][j], 0, 0, 0);
        __syncthreads();
    }
    // ---- fused epilogue: band dots, atomic global reduce ----
    int colg[4]; float ub[4], vb[4];
#pragma unroll
    for (int j = 0; j < 4; j++) {
        colg[j] = n0 + wc * 64 + j * 16 + (lane & 15);
        ub[j] = u[colg[j]];
        vb[j] = v[colg[j]];
    }
#pragma unroll
    for (int i = 0; i < 2; i++) {
#pragma unroll
        for (int rr = 0; rr < 4; rr++) {
            const int row = m0 + wr * 32 + i * 16 + (lane >> 4) * 4 + rr;
            const int rm = (row == 0) ? 0 : row - 1;
            const int rp = (row == MM - 1) ? MM - 1 : row + 1;
            const __bf16* hm = A + (size_t)rm * DD;
            const __bf16* hz = A + (size_t)row * DD;
            const __bf16* hp = A + (size_t)rp * DD;
            float dua = 0.f, dna = 0.f, wa = 0.f;
#pragma unroll
            for (int j = 0; j < 4; j++) {
                const float Rv = acc[i][j][rr] + ub[j];
                dua += Rv * (float)hm[colg[j]];
                dna += Rv * (float)hp[colg[j]];
                wa  += vb[j] * (float)hz[colg[j]];
            }
#pragma unroll
            for (int o = 1; o < 16; o <<= 1) {
                dua += __shfl_xor(dua, o);
                dna += __shfl_xor(dna, o);
                wa  += __shfl_xor(wa, o);
            }
            if ((lane & 15) == 0) {
                atomicAdd(&du_g[row], dua);
                atomicAdd(&dn_g[row], dna);
                atomicAdd(&w_g[row], wa);
            }
        }
    }
}

// ============ K2: per-batch softmax, nb, log2, double prefix scan ============
__global__ __launch_bounds__(256) void scan_kernel(const float* __restrict__ du_g,
        const float* __restrict__ dn_g, const float* __restrict__ w_g,
        const float* __restrict__ cbp, const int* __restrict__ fl_i,
        const float* __restrict__ prsup,
        float* __restrict__ nb, double* __restrict__ P2) {
    const int b = blockIdx.x;
    const int t = threadIdx.x;
    __shared__ float du_s[SS], dn_s[SS], w_s[SS], sh_pd[SS];
    __shared__ double warr[256];
    for (int x = t; x < SS; x += 256) {
        du_s[x] = du_g[b * SS + x];
        dn_s[x] = dn_g[b * SS + x];
        w_s[x]  = w_g[b * SS + x];
    }
    __syncthreads();
    const float cb = cbp[0];
    float pu_r[8];
#pragma unroll
    for (int e = 0; e < 8; e++) {
        const int s = t * 8 + e;
        const int fl = fl_i[b * SS + s];
        const bool au = fl & 1, ad = fl & 2;
        float puv = 0.f, pdv = 0.f;
        if (au || ad) {
            const float eu = au ? (du_s[s + 1] + w_s[s + 1] + cb) * (1.0f / DD) : 0.f;
            const float ed = ad ? (dn_s[s - 1] + w_s[s - 1] + cb) * (1.0f / DD) : 0.f;
            float mx = au ? eu : ed;
            if (au && ad) mx = fmaxf(eu, ed);
            const float zu = au ? expf(eu - mx) : 0.f;
            const float zd = ad ? expf(ed - mx) : 0.f;
            const float iz = 1.f / (zu + zd);
            puv = zu * iz; pdv = zd * iz;
        }
        pu_r[e] = puv;
        sh_pd[s] = pdv;
    }
    __syncthreads();
    double L[8];
    double mysum = 0.0;
#pragma unroll
    for (int e = 0; e < 8; e++) {
        const int s = t * 8 + e;
        double Lv = 0.0;
        float nbv = 0.f;
        if (s < SS - 1) {
            nbv = sqrtf(pu_r[e] * sh_pd[s + 1] + 1e-9f);
            const float pr = prsup[b * SS + s];
            const float nsup = pr + (1.f - pr) * nbv;
            Lv = (double)log2f(nsup + 1e-9f);
        }
        nb[b * SS + s] = nbv;
        L[e] = Lv; mysum += Lv;
    }
    warr[t] = mysum;
    __syncthreads();
    for (int o = 1; o < 256; o <<= 1) {
        double vv = 0.0;
        if (t >= o) vv = warr[t - o];
        __syncthreads();
        if (t >= o) warr[t] += vv;
        __syncthreads();
    }
    double run = warr[t] - mysum;    // exclusive prefix across threads
#pragma unroll
    for (int e = 0; e < 8; e++) {
        P2[(size_t)b * SS + t * 8 + e] = run;
        run += L[e];
    }
}

// ============ K3: fused elementwise output (g and n), 8 elems/thread ============
__global__ __launch_bounds__(256) void out_kernel(const float* __restrict__ prior,
        const float* __restrict__ nb, const double* __restrict__ P2,
        float* __restrict__ gout, float* __restrict__ nout) {
    const size_t t8 = (size_t)blockIdx.x * 256 + threadIdx.x;
    const int b = (int)(t8 >> 19);                 // (t8*8) / (SS*SS)
    const size_t off = t8 << 3;                    // element base
    const size_t r = off & ((1u << 22) - 1);
    const int i  = (int)(r >> 11);                 // row
    const int k0 = (int)(r & 2047);                // col base
    const f32x4 p0 = *(const f32x4*)(prior + off);
    const f32x4 p1 = *(const f32x4*)(prior + off + 4);
    const double* Pb = P2 + ((size_t)b << 11);
    const double Pi = Pb[i];
    const float* nbb = nb + ((size_t)b << 11);
    f32x4 g0, g1, n0, n1;
#pragma unroll
    for (int c = 0; c < 8; c++) {
        const int k = k0 + c;
        const float pr = (c < 4) ? p0[c] : p1[c - 4];
        float vv = 3.16227766016838e-5f;           // sqrt(1e-9)
        if (k == i + 1)      vv = nbb[i];
        else if (k == i - 1) vv = nbb[k];
        const float nval = pr + (1.f - pr) * vv;
        float g;
        if (k == i) {
            g = nval;
        } else {
            const double Pk = Pb[k];
            const double dd = (k > i) ? (Pk - Pi) : (Pi - Pk);
            g = exp2f((float)dd) + 1e-9f;
        }
        if (c < 4) { g0[c] = g; n0[c] = nval; }
        else       { g1[c - 4] = g; n1[c - 4] = nval; }
    }
    *(f32x4*)(gout + off)     = g0;
    *(f32x4*)(gout + off + 4) = g1;
    *(f32x4*)(nout + off)     = n0;
    *(f32x4*)(nout + off + 4) = n1;
}

extern "C" void kernel_launch(void* const* d_in, const int* in_sizes, int n_in,
                              void* d_out, int out_size, void* d_ws, size_t ws_size,
                              hipStream_t stream) {
    const float* hs    = (const float*)d_in[0];
    const int*   att   = (const int*)d_in[1];
    const float* prior = (const float*)d_in[2];
    const float* ln_w  = (const float*)d_in[3];
    const float* ln_b  = (const float*)d_in[4];
    const float* wq    = (const float*)d_in[5];
    const float* bq    = (const float*)d_in[6];
    const float* wk    = (const float*)d_in[7];
    const float* bk    = (const float*)d_in[8];

    float* gout = (float*)d_out;                       // g first (return order)
    float* nout = gout + (size_t)BB * SS * SS;

    char* ws = (char*)d_ws;
    __bf16* h     = (__bf16*)(ws);                     // 12,582,912
    __bf16* G     = (__bf16*)(ws + 12582912);          //  1,179,648
    float*  u     = (float*) (ws + 13762560);          //      3,072
    float*  v     = (float*) (ws + 13765632);          //      3,072
    float*  cbp   = (float*) (ws + 13768704);          //        256
    int*    fl    = (int*)   (ws + 13768960);          //     32,768
    float*  prsup = (float*) (ws + 13801728);          //     32,768
    float*  du_g  = (float*) (ws + 13834496);          //     32,768
    float*  dn_g  = (float*) (ws + 13867264);          //     32,768
    float*  w_g   = (float*) (ws + 13900032);          //     32,768
    float*  nbuf  = (float*) (ws + 13932800);          //     32,768
    double* P2    = (double*)(ws + 13965568);          //     65,536

    combined_kernel<<<dim3(2609), dim3(256), 0, stream>>>(hs, ln_w, ln_b, wq, wk, bq, bk,
                                                          att, prior, G, u, v, cbp, h, fl, prsup,
                                                          du_g, dn_g, w_g);
    rgemm_kernel<<<dim3(768), dim3(256), 0, stream>>>(h, G, u, v, du_g, dn_g, w_g);
    scan_kernel<<<dim3(BB), dim3(256), 0, stream>>>(du_g, dn_g, w_g, cbp, fl, prsup, nbuf, P2);
    out_kernel<<<dim3((BB * SS * SS / 8) / 256), dim3(256), 0, stream>>>(prior, nbuf, P2, gout, nout);
}